// Round 1
// baseline (380.049 us; speedup 1.0000x reference)
//
#include <hip/hip_runtime.h>

// RandomShiftsAug on MI355X.
// Mathematical simplification: the reference's pad+grid_sample collapses to
//   out[n,c,i,j] = x[n,c, clamp(i+sy-4,0,H-1), clamp(j+sx-4,0,W-1)]
// where (sx,sy) = shift[n] in [0,8]. Pure memory-bound shifted copy.

constexpr int PADC = 4;
constexpr int Nn = 128, Cc = 9, Hh = 224, Ww = 224;

__global__ __launch_bounds__(256) void shift_gather(
    const float* __restrict__ x, const int* __restrict__ shift,
    float* __restrict__ out)
{
    constexpr int W4          = Ww / 4;        // 56 float4 per row
    constexpr int vec_per_img = Cc * Hh * W4;  // 112896
    const long total = (long)Nn * vec_per_img; // 14,450,688

    long idx = (long)blockIdx.x * blockDim.x + threadIdx.x;
    if (idx >= total) return;

    int n   = (int)(idx / vec_per_img);
    int r   = (int)(idx - (long)n * vec_per_img);
    int chw = r / W4;             // c*Hh + i
    int j4  = r - chw * W4;       // float4 index within row
    int i   = chw % Hh;

    // shift layout: (n,1,1,2) int32; [...,0] = width shift, [...,1] = height shift
    int sx = shift[2 * n + 0] - PADC;   // [-4, 4]
    int sy = shift[2 * n + 1] - PADC;

    int si = min(max(i + sy, 0), Hh - 1);

    // source row pointer: n*C*H + c*H + si  (c*H == chw - i)
    const float* srow = x + ((long)n * Cc * Hh + (chw - i) + si) * (long)Ww;

    int j0 = 4 * j4;
    int jb = j0 + sx;
    // Unconditional clamp: only edge float4s actually clamp, but branchless
    // avoids divergence; 8 extra VALU ops per thread is free vs HBM.
    float v0 = srow[min(max(jb    , 0), Ww - 1)];
    float v1 = srow[min(max(jb + 1, 0), Ww - 1)];
    float v2 = srow[min(max(jb + 2, 0), Ww - 1)];
    float v3 = srow[min(max(jb + 3, 0), Ww - 1)];

    float4 v = make_float4(v0, v1, v2, v3);
    *(float4*)(out + ((long)chw + (long)n * Cc * Hh) * Ww + j0) = v;
}

extern "C" void kernel_launch(void* const* d_in, const int* in_sizes, int n_in,
                              void* d_out, int out_size, void* d_ws, size_t ws_size,
                              hipStream_t stream) {
    const float* x     = (const float*)d_in[0];
    const int*   shift = (const int*)d_in[1];
    float*       out   = (float*)d_out;

    constexpr long total = (long)Nn * Cc * Hh * (Ww / 4);   // 14,450,688
    constexpr int  block = 256;
    const long grid = (total + block - 1) / block;          // 56448

    hipLaunchKernelGGL(shift_gather, dim3((unsigned)grid), dim3(block), 0, stream,
                       x, shift, out);
}

// Round 2
// 374.359 us; speedup vs baseline: 1.0152x; 1.0152x over previous
//
#include <hip/hip_runtime.h>

// RandomShiftsAug on MI355X.
// Math: reference's replicate-pad + grid_sample collapses (exactly, up to fp32
// grid rounding ~1e-5 px) to an integer translation with edge clamp:
//   out[n,c,i,j] = x[n,c, clamp(i+sy-4,0,223), clamp(j+sx-4,0,223)]
// shift[n,...,0] = sx (width), shift[n,...,1] = sy (height), in [0,8].
//
// Round-1 lesson: 4 scalar strided loads/thread ran at 1.2 TB/s (380 us).
// This version: ONE misaligned global_load_dwordx4 per thread (gfx950 VMEM
// needs only 4B alignment) + branchless component-select fixup for the <=1
// left / <=1 right edge vector per row. Grid (56,9,128) -> no int div/mod;
// shift[] reads are block-uniform (scalar loads).

constexpr int PADC = 4;
constexpr int Nn = 128, Cc = 9, Hh = 224, Ww = 224;

typedef float f4u __attribute__((ext_vector_type(4), aligned(4)));  // unaligned-load view
typedef float f4a __attribute__((ext_vector_type(4)));              // aligned store

__device__ __forceinline__ float pick4(f4a v, int s) {
    // s in [0,3] -> v[s]; 3 cndmask
    float lo = (s & 1) ? v.y : v.x;
    float hi = (s & 1) ? v.w : v.z;
    return (s & 2) ? hi : lo;
}

__global__ __launch_bounds__(256) void shift_gather(
    const float* __restrict__ x, const int* __restrict__ shift,
    float* __restrict__ out)
{
    const int j4 = threadIdx.x & 63;       // float4 index within row
    if (j4 >= Ww / 4) return;              // lanes 56..63 idle (no mem traffic)
    const int wave = threadIdx.x >> 6;     // 0..3 -> row within block
    const int i = blockIdx.x * 4 + wave;   // image row, 0..223
    const int c = blockIdx.y;              // channel, 0..8
    const int n = blockIdx.z;              // batch, 0..127

    // block-uniform -> compiler emits scalar loads
    const int sx = shift[2 * n + 0] - PADC;   // [-4, 4]
    const int sy = shift[2 * n + 1] - PADC;

    const int si = min(max(i + sy, 0), Hh - 1);
    const long img = (long)(n * Cc + c) * Hh;
    const float* __restrict__ srow = x + (img + si) * Ww;

    const int j0  = j4 * 4;                       // [0, 220]
    const int jb  = j0 + sx;                      // [-4, 224]
    const int jbc = min(max(jb, 0), Ww - 4);      // clamped vector base [0,220]

    f4a v = *(const f4u*)(srow + jbc);            // single dwordx4, 4B-aligned OK

    // component k wants srow[clamp(jb+k,0,223)] == v[clamp(jb+k,0,223)-jbc],
    // and that select index is provably in [0,3]. Interior lanes: s==k.
    int s0 = min(max(jb + 0, 0), Ww - 1) - jbc;
    int s1 = min(max(jb + 1, 0), Ww - 1) - jbc;
    int s2 = min(max(jb + 2, 0), Ww - 1) - jbc;
    int s3 = min(max(jb + 3, 0), Ww - 1) - jbc;

    f4a o;
    o.x = pick4(v, s0);
    o.y = pick4(v, s1);
    o.z = pick4(v, s2);
    o.w = pick4(v, s3);

    float* drow = out + (img + i) * Ww;
    *(f4a*)(drow + j0) = o;                       // 16B-aligned, full-line rows
}

extern "C" void kernel_launch(void* const* d_in, const int* in_sizes, int n_in,
                              void* d_out, int out_size, void* d_ws, size_t ws_size,
                              hipStream_t stream) {
    const float* x     = (const float*)d_in[0];
    const int*   shift = (const int*)d_in[1];
    float*       out   = (float*)d_out;

    dim3 grid(Hh / 4, Cc, Nn);   // (56, 9, 128): blockIdx -> (row group, c, n)
    dim3 block(256);             // 4 waves = 4 rows; lanes 0..55 active per wave
    hipLaunchKernelGGL(shift_gather, grid, block, 0, stream, x, shift, out);
}

// Round 3
// 359.125 us; speedup vs baseline: 1.0583x; 1.0424x over previous
//
#include <hip/hip_runtime.h>

// RandomShiftsAug on MI355X.
// Math: replicate-pad + grid_sample collapses (exactly, up to ~1e-5 px fp32
// grid rounding) to an integer translation with edge clamp:
//   out[n,c,i,j] = x[n,c, clamp(i+sy-4,0,223), clamp(j+sx-4,0,223)]
// shift[n,...,0] = sx (width), shift[n,...,1] = sy (height), in [0,8].
//
// HBM floor: 231 MB read + 231 MB write = 462 MB @ ~6.3 TB/s achievable
// => ~73 us. R1 evidence says the kernel itself is already <140 us (absent
// from top-5 dispatch durations) and bench dur_us carries ~300 us of harness
// restore/poison. This version: full 64-lane utilization (12544 vec4/image
// = 49 blocks x 256 threads exactly), one misaligned global_load_dwordx4
// per thread (4B alignment is legal on gfx950 VMEM), branchless edge
// component-select, nontemporal load/store (streaming, zero reuse).

constexpr int PADC = 4;
constexpr int Nn = 128, Cc = 9, Hh = 224, Ww = 224;
constexpr int W4 = Ww / 4;              // 56 vec4 per row
constexpr int VEC_PER_IMG = Hh * W4;    // 12544 = 49 * 256

typedef float f4u __attribute__((ext_vector_type(4), aligned(4)));  // 4B-aligned load view
typedef float f4a __attribute__((ext_vector_type(4)));              // 16B-aligned store

__device__ __forceinline__ float pick4(f4a v, int s) {
    // s in [0,3] -> v[s]; 3 v_cndmask
    float lo = (s & 1) ? v.y : v.x;
    float hi = (s & 1) ? v.w : v.z;
    return (s & 2) ? hi : lo;
}

__global__ __launch_bounds__(256) void shift_gather(
    const float* __restrict__ x, const int* __restrict__ shift,
    float* __restrict__ out)
{
    const int t  = blockIdx.x * 256 + threadIdx.x;  // vec4 index in image, 0..12543
    const int i  = t / W4;                          // row 0..223 (magic-mul div)
    const int j4 = t - i * W4;                      // vec4 col 0..55
    const int c  = blockIdx.y;                      // 0..8
    const int n  = blockIdx.z;                      // 0..127

    // block-uniform -> scalar loads
    const int sx = shift[2 * n + 0] - PADC;         // [-4, 4]
    const int sy = shift[2 * n + 1] - PADC;

    const int si = min(max(i + sy, 0), Hh - 1);
    const long img = (long)(n * Cc + c) * Hh;
    const float* __restrict__ srow = x + (img + si) * Ww;

    const int j0  = j4 * 4;                         // [0, 220]
    const int jb  = j0 + sx;                        // [-4, 224]
    const int jbc = min(max(jb, 0), Ww - 4);        // clamped vector base [0, 220]

    f4a v = __builtin_nontemporal_load((const f4u*)(srow + jbc));  // one dwordx4 nt

    // component k wants srow[clamp(jb+k,0,223)] == v[clamp(jb+k,0,223)-jbc],
    // select index provably in [0,3]; interior lanes reduce to identity.
    int s0 = min(max(jb + 0, 0), Ww - 1) - jbc;
    int s1 = min(max(jb + 1, 0), Ww - 1) - jbc;
    int s2 = min(max(jb + 2, 0), Ww - 1) - jbc;
    int s3 = min(max(jb + 3, 0), Ww - 1) - jbc;

    f4a o;
    o.x = pick4(v, s0);
    o.y = pick4(v, s1);
    o.z = pick4(v, s2);
    o.w = pick4(v, s3);

    __builtin_nontemporal_store(o, (f4a*)(out + (img + i) * Ww + j0));
}

extern "C" void kernel_launch(void* const* d_in, const int* in_sizes, int n_in,
                              void* d_out, int out_size, void* d_ws, size_t ws_size,
                              hipStream_t stream) {
    const float* x     = (const float*)d_in[0];
    const int*   shift = (const int*)d_in[1];
    float*       out   = (float*)d_out;

    dim3 grid(VEC_PER_IMG / 256, Cc, Nn);   // (49, 9, 128), exact tiling
    dim3 block(256);
    hipLaunchKernelGGL(shift_gather, grid, block, 0, stream, x, shift, out);
}